// Round 1
// baseline (116.902 us; speedup 1.0000x reference)
//
#include <hip/hip_runtime.h>
#include <math.h>

#define ALPHA 0.25f

constexpr int B = 8, A = 100000, C = 80, M = 32;
constexpr int APB = 256;                       // anchors per block
constexpr int NBLK = (A + APB - 1) / APB;      // 391

__global__ __launch_bounds__(256) void focal_main(
    const float* __restrict__ cls,       // [B,A,C]
    const float* __restrict__ regs,      // [B,A,4]
    const float* __restrict__ anchors,   // [1,A,4]
    const float* __restrict__ ann,       // [B,M,5]
    float* __restrict__ cls_acc,         // [B]
    float* __restrict__ reg_acc,         // [B]
    unsigned int* __restrict__ npos_acc) // [B]
{
    const int b   = blockIdx.y;
    const int a0  = blockIdx.x * APB;
    const int tid = threadIdx.x;
    const int nA  = min(APB, A - a0);

    __shared__ float bx1[M], by1[M], bx2[M], by2[M], blab[M], barea[M];
    __shared__ int codes[APB];           // -1 ignore, C = negative, 0..C-1 = positive label
    __shared__ float rc[4], rr[4];
    __shared__ int   rp[4];

    if (tid < M) {
        const float* p = ann + ((size_t)b * M + tid) * 5;
        float x1 = p[0], y1 = p[1], x2 = p[2], y2 = p[3];
        bx1[tid] = x1; by1[tid] = y1; bx2[tid] = x2; by2[tid] = y2;
        blab[tid] = p[4];
        barea[tid] = (x2 - x1) * (y2 - y1);
    }
    __syncthreads();

    float my_reg = 0.f;
    int   my_pos = 0;
    int   code   = -1;                   // default: contributes nothing (also for tail threads)
    const int a = a0 + tid;
    if (tid < nA) {
        float4 ab = *(const float4*)(anchors + (size_t)a * 4);
        const float ax1 = ab.x, ay1 = ab.y, ax2 = ab.z, ay2 = ab.w;
        const float area_a = (ax2 - ax1) * (ay2 - ay1);
        float best = -2.f; int barg = 0;
        #pragma unroll
        for (int m = 0; m < M; ++m) {
            float iw = fminf(ax2, bx2[m]) - fmaxf(ax1, bx1[m]);
            float ih = fminf(ay2, by2[m]) - fmaxf(ay1, by1[m]);
            iw = fmaxf(iw, 0.f); ih = fmaxf(ih, 0.f);
            float inter = iw * ih;
            float ua  = fmaxf(area_a + barea[m] - inter, 1e-8f);
            float iou = inter / ua;
            if (blab[m] == -1.0f) iou = -1.0f;   // invalid annotation mask
            if (iou > best) { best = iou; barg = m; }
        }
        const bool pos = best >= 0.4f;   // IOU_THR + 0.1
        const bool neg = best < 0.3f;    // IOU_THR
        code = pos ? (int)blab[barg] : (neg ? C : -1);
        if (pos) {
            my_pos = 1;
            const float aw = ax2 - ax1, ah = ay2 - ay1;
            const float acx = ax1 + 0.5f * aw, acy = ay1 + 0.5f * ah;
            float gw = bx2[barg] - bx1[barg], gh = by2[barg] - by1[barg];
            const float gcx = bx1[barg] + 0.5f * gw, gcy = by1[barg] + 0.5f * gh;
            gw = fmaxf(gw, 1.f); gh = fmaxf(gh, 1.f);
            const float t0 = ((gcx - acx) / aw) / 0.1f;
            const float t1 = ((gcy - acy) / ah) / 0.1f;
            const float t2 = __logf(gw / aw) / 0.2f;
            const float t3 = __logf(gh / ah) / 0.2f;
            float4 rp4 = *(const float4*)(regs + ((size_t)b * A + a) * 4);
            const float d0 = fabsf(t0 - rp4.x), d1 = fabsf(t1 - rp4.y);
            const float d2 = fabsf(t2 - rp4.z), d3 = fabsf(t3 - rp4.w);
            my_reg = (d0 <= 1.f ? 0.5f * d0 * d0 : d0 - 0.5f)
                   + (d1 <= 1.f ? 0.5f * d1 * d1 : d1 - 0.5f)
                   + (d2 <= 1.f ? 0.5f * d2 * d2 : d2 - 0.5f)
                   + (d3 <= 1.f ? 0.5f * d3 * d3 : d3 - 0.5f);
        }
    }
    codes[tid] = code;
    __syncthreads();

    // ---- Phase 2: focal BCE over the contiguous [nA x C] chunk, float4-coalesced
    float my_cls = 0.f;
    const float* base = cls + ((size_t)b * A + a0) * C;
    const int n4 = nA * (C / 4);
    for (int i = tid; i < n4; i += APB) {
        const int anch = i / (C / 4);
        const int cb   = (i - anch * (C / 4)) * 4;
        const int cd   = codes[anch];
        if (cd < 0) continue;            // ignore band: targets == -1 everywhere
        float4 v = *(const float4*)(base + (size_t)i * 4);
        float pv[4] = {v.x, v.y, v.z, v.w};
        #pragma unroll
        for (int j = 0; j < 4; ++j) {
            const float p  = fminf(fmaxf(pv[j], 1e-4f), 0.9999f);
            const bool  tp = (cb + j) == cd;
            const float af = tp ? ALPHA : (1.f - ALPHA);
            const float w  = tp ? (1.f - p) : p;
            const float lg = tp ? p : (1.f - p);
            my_cls += af * w * w * (-__logf(lg));
        }
    }

    // ---- block reduction
    #pragma unroll
    for (int off = 32; off; off >>= 1) {
        my_cls += __shfl_down(my_cls, off);
        my_reg += __shfl_down(my_reg, off);
        my_pos += __shfl_down(my_pos, off);
    }
    const int wid = tid >> 6;
    if ((tid & 63) == 0) { rc[wid] = my_cls; rr[wid] = my_reg; rp[wid] = my_pos; }
    __syncthreads();
    if (tid == 0) {
        atomicAdd(&cls_acc[b], rc[0] + rc[1] + rc[2] + rc[3]);
        atomicAdd(&reg_acc[b], rr[0] + rr[1] + rr[2] + rr[3]);
        atomicAdd(&npos_acc[b], (unsigned)(rp[0] + rp[1] + rp[2] + rp[3]));
    }
}

__global__ void focal_finalize(const float* __restrict__ cls_acc,
                               const float* __restrict__ reg_acc,
                               const unsigned int* __restrict__ npos_acc,
                               float* __restrict__ out)
{
    if (threadIdx.x == 0) {
        float cm = 0.f, rm = 0.f; unsigned tot = 0u;
        #pragma unroll
        for (int b = 0; b < B; ++b) {
            const unsigned np = npos_acc[b];
            const float npf = (float)np;
            cm += cls_acc[b] / fmaxf(npf, 1.f);
            rm += (np > 0u) ? reg_acc[b] / fmaxf(npf * 4.f, 1.f) : 0.f;
            tot += np;
        }
        out[0] = cm / (float)B;
        out[1] = rm / (float)B;
        out[2] = (float)tot;
    }
}

extern "C" void kernel_launch(void* const* d_in, const int* in_sizes, int n_in,
                              void* d_out, int out_size, void* d_ws, size_t ws_size,
                              hipStream_t stream) {
    const float* cls     = (const float*)d_in[0];
    const float* regs    = (const float*)d_in[1];
    const float* anchors = (const float*)d_in[2];
    const float* ann     = (const float*)d_in[3];
    float* out = (float*)d_out;

    float* cls_acc = (float*)d_ws;
    float* reg_acc = cls_acc + B;
    unsigned int* npos_acc = (unsigned int*)(reg_acc + B);

    hipMemsetAsync(d_ws, 0, 2 * B * sizeof(float) + B * sizeof(unsigned int), stream);

    dim3 grid(NBLK, B);
    focal_main<<<grid, APB, 0, stream>>>(cls, regs, anchors, ann,
                                         cls_acc, reg_acc, npos_acc);
    focal_finalize<<<1, 64, 0, stream>>>(cls_acc, reg_acc, npos_acc, out);
}

// Round 2
// 107.328 us; speedup vs baseline: 1.0892x; 1.0892x over previous
//
#include <hip/hip_runtime.h>
#include <math.h>

constexpr int B = 8, A = 100000, C = 80, M = 32;
constexpr int APB = 256;                       // anchors per block
constexpr int NBLK = (A + APB - 1) / APB;      // 391
constexpr int C4  = C / 4;                     // 20 float4 per anchor
// every valid (pos or neg) element contributes 0.75*p^2*(-ln(1-p));
// fold -(ln2)*0.75 into the per-anchor scale for use with __log2f.
#define SNEG (-0.6931472f * 0.75f)

__global__ __launch_bounds__(256) void focal_main(
    const float* __restrict__ cls,       // [B,A,C]
    const float* __restrict__ regs,      // [B,A,4]
    const float* __restrict__ anchors,   // [1,A,4]
    const float* __restrict__ ann,       // [B,M,5]
    float* __restrict__ cls_acc,         // [B]
    float* __restrict__ reg_acc,         // [B]
    unsigned int* __restrict__ npos_acc) // [B]
{
    const int b   = blockIdx.y;
    const int a0  = blockIdx.x * APB;
    const int tid = threadIdx.x;
    const int nA  = min(APB, A - a0);

    __shared__ float bx1[M], by1[M], bx2[M], by2[M], blab[M], barea[M];
    __shared__ float sneg[APB];          // per-anchor scale: SNEG (valid) or 0 (ignore/tail)
    __shared__ float rc[4], rr[4];
    __shared__ int   rp[4];

    if (tid < M) {
        const float* p = ann + ((size_t)b * M + tid) * 5;
        float x1 = p[0], y1 = p[1], x2 = p[2], y2 = p[3];
        bx1[tid] = x1; by1[tid] = y1; bx2[tid] = x2; by2[tid] = y2;
        blab[tid] = p[4];
        barea[tid] = (x2 - x1) * (y2 - y1);
    }
    __syncthreads();

    float my_cls = 0.f, my_reg = 0.f;
    int   my_pos = 0;
    float scale  = 0.f;
    const int a = a0 + tid;
    if (tid < nA) {
        float4 ab = *(const float4*)(anchors + (size_t)a * 4);
        const float ax1 = ab.x, ay1 = ab.y, ax2 = ab.z, ay2 = ab.w;
        const float area_a = (ax2 - ax1) * (ay2 - ay1);
        float best = -2.f; int barg = 0;
        #pragma unroll
        for (int m = 0; m < M; ++m) {
            float iw = fminf(ax2, bx2[m]) - fmaxf(ax1, bx1[m]);
            float ih = fminf(ay2, by2[m]) - fmaxf(ay1, by1[m]);
            iw = fmaxf(iw, 0.f); ih = fmaxf(ih, 0.f);
            float inter = iw * ih;
            float ua  = fmaxf(area_a + barea[m] - inter, 1e-8f);
            float iou = inter / ua;
            if (blab[m] == -1.0f) iou = -1.0f;   // invalid annotation mask
            if (iou > best) { best = iou; barg = m; }
        }
        const bool pos = best >= 0.4f;   // IOU_THR + 0.1
        const bool neg = best < 0.3f;    // IOU_THR
        scale = (pos || neg) ? SNEG : 0.f;
        if (pos) {
            my_pos = 1;
            const int cd = (int)blab[barg];
            // correction for the one target column: replace neg-term with pos-term
            float p = cls[((size_t)b * A + a) * C + cd];
            p = fminf(fmaxf(p, 1e-4f), 0.9999f);
            const float omp = 1.f - p;
            my_cls = 0.25f * omp * omp * (-__logf(p))
                   - 0.75f * p * p * (-__logf(omp));
            // regression smooth-L1
            const float aw = ax2 - ax1, ah = ay2 - ay1;
            const float acx = ax1 + 0.5f * aw, acy = ay1 + 0.5f * ah;
            float gw = bx2[barg] - bx1[barg], gh = by2[barg] - by1[barg];
            const float gcx = bx1[barg] + 0.5f * gw, gcy = by1[barg] + 0.5f * gh;
            gw = fmaxf(gw, 1.f); gh = fmaxf(gh, 1.f);
            const float t0 = ((gcx - acx) / aw) / 0.1f;
            const float t1 = ((gcy - acy) / ah) / 0.1f;
            const float t2 = __logf(gw / aw) / 0.2f;
            const float t3 = __logf(gh / ah) / 0.2f;
            float4 rp4 = *(const float4*)(regs + ((size_t)b * A + a) * 4);
            const float d0 = fabsf(t0 - rp4.x), d1 = fabsf(t1 - rp4.y);
            const float d2 = fabsf(t2 - rp4.z), d3 = fabsf(t3 - rp4.w);
            my_reg = (d0 <= 1.f ? 0.5f * d0 * d0 : d0 - 0.5f)
                   + (d1 <= 1.f ? 0.5f * d1 * d1 : d1 - 0.5f)
                   + (d2 <= 1.f ? 0.5f * d2 * d2 : d2 - 0.5f)
                   + (d3 <= 1.f ? 0.5f * d3 * d3 : d3 - 0.5f);
        }
    }
    sneg[tid] = scale;
    __syncthreads();

    // ---- Phase 2: focal BCE (negative-class formula everywhere) over the
    // contiguous [nA x C] chunk; 5 float4 loads in flight per wave.
    const float* base = cls + ((size_t)b * A + a0) * C;
    if (nA == APB) {
        #pragma unroll 1
        for (int batch = 0; batch < 4; ++batch) {
            const int i0 = tid + batch * (5 * APB);
            float4 v0 = *(const float4*)(base + (size_t)(i0          ) * 4);
            float4 v1 = *(const float4*)(base + (size_t)(i0 +     APB) * 4);
            float4 v2 = *(const float4*)(base + (size_t)(i0 + 2 * APB) * 4);
            float4 v3 = *(const float4*)(base + (size_t)(i0 + 3 * APB) * 4);
            float4 v4 = *(const float4*)(base + (size_t)(i0 + 4 * APB) * 4);
            float4 vv[5] = {v0, v1, v2, v3, v4};
            #pragma unroll
            for (int k = 0; k < 5; ++k) {
                const int i = i0 + k * APB;
                const float s = sneg[i / C4];
                const float pv[4] = {vv[k].x, vv[k].y, vv[k].z, vv[k].w};
                #pragma unroll
                for (int j = 0; j < 4; ++j) {
                    const float p = fminf(fmaxf(pv[j], 1e-4f), 0.9999f);
                    const float t = __log2f(1.f - p);
                    my_cls = fmaf(s, p * p * t, my_cls);
                }
            }
        }
    } else {
        const int n4 = nA * C4;
        for (int i = tid; i < n4; i += APB) {
            const float s = sneg[i / C4];
            float4 v = *(const float4*)(base + (size_t)i * 4);
            const float pv[4] = {v.x, v.y, v.z, v.w};
            #pragma unroll
            for (int j = 0; j < 4; ++j) {
                const float p = fminf(fmaxf(pv[j], 1e-4f), 0.9999f);
                const float t = __log2f(1.f - p);
                my_cls = fmaf(s, p * p * t, my_cls);
            }
        }
    }

    // ---- block reduction
    #pragma unroll
    for (int off = 32; off; off >>= 1) {
        my_cls += __shfl_down(my_cls, off);
        my_reg += __shfl_down(my_reg, off);
        my_pos += __shfl_down(my_pos, off);
    }
    const int wid = tid >> 6;
    if ((tid & 63) == 0) { rc[wid] = my_cls; rr[wid] = my_reg; rp[wid] = my_pos; }
    __syncthreads();
    if (tid == 0) {
        atomicAdd(&cls_acc[b], rc[0] + rc[1] + rc[2] + rc[3]);
        atomicAdd(&reg_acc[b], rr[0] + rr[1] + rr[2] + rr[3]);
        atomicAdd(&npos_acc[b], (unsigned)(rp[0] + rp[1] + rp[2] + rp[3]));
    }
}

__global__ void focal_finalize(const float* __restrict__ cls_acc,
                               const float* __restrict__ reg_acc,
                               const unsigned int* __restrict__ npos_acc,
                               float* __restrict__ out)
{
    if (threadIdx.x == 0) {
        float cm = 0.f, rm = 0.f; unsigned tot = 0u;
        #pragma unroll
        for (int b = 0; b < B; ++b) {
            const unsigned np = npos_acc[b];
            const float npf = (float)np;
            cm += cls_acc[b] / fmaxf(npf, 1.f);
            rm += (np > 0u) ? reg_acc[b] / fmaxf(npf * 4.f, 1.f) : 0.f;
            tot += np;
        }
        out[0] = cm / (float)B;
        out[1] = rm / (float)B;
        out[2] = (float)tot;
    }
}

extern "C" void kernel_launch(void* const* d_in, const int* in_sizes, int n_in,
                              void* d_out, int out_size, void* d_ws, size_t ws_size,
                              hipStream_t stream) {
    const float* cls     = (const float*)d_in[0];
    const float* regs    = (const float*)d_in[1];
    const float* anchors = (const float*)d_in[2];
    const float* ann     = (const float*)d_in[3];
    float* out = (float*)d_out;

    float* cls_acc = (float*)d_ws;
    float* reg_acc = cls_acc + B;
    unsigned int* npos_acc = (unsigned int*)(reg_acc + B);

    hipMemsetAsync(d_ws, 0, 2 * B * sizeof(float) + B * sizeof(unsigned int), stream);

    dim3 grid(NBLK, B);
    focal_main<<<grid, APB, 0, stream>>>(cls, regs, anchors, ann,
                                         cls_acc, reg_acc, npos_acc);
    focal_finalize<<<1, 64, 0, stream>>>(cls_acc, reg_acc, npos_acc, out);
}